// Round 4
// baseline (350.614 us; speedup 1.0000x reference)
//
#include <hip/hip_runtime.h>

// LSTM scan, B=8192 chains, T=2048 steps, D=H=2.
// 4 lanes per batch element (quad); cross-lane via DPP quad_perm.
// Round-4 change: nonlinearities via clamped Pade(5,4) rational tanh
// (no exp2 on the critical chain; sigmoid = 0.5+0.5*tanh(x/2) with the
// 0.5 arg-scale folded into weights and the affine folded into the
// existing per-lane fma slot). x streamed through 2x8-float4 register
// double-buffer (unchanged from round 3).

template <int CTRL>
__device__ __forceinline__ float qperm(float v) {
    int i = __builtin_bit_cast(int, v);
    i = __builtin_amdgcn_update_dpp(0, i, CTRL, 0xf, 0xf, true);
    return __builtin_bit_cast(float, i);
}
#define QP_BCAST0 0x00  // (0,0,0,0)
#define QP_BCAST1 0x55  // (1,1,1,1)
#define QP_SWAP2  0x4E  // (2,3,0,1)

// tanh(x) ~= x*(x^4+105x^2+945)/(15x^4+420x^2+945), clamped to [-1,1].
// |err| <= ~4e-4 for |x|<3.8; clamp exact beyond. No transcendental but rcp.
__device__ __forceinline__ float tanh_pade(float x) {
    float x2 = x * x;
    float num = fmaf(x2 + 105.0f, x2, 945.0f) * x;
    float den = fmaf(fmaf(x2, 15.0f, 420.0f), x2, 945.0f);
    float t = num * __builtin_amdgcn_rcpf(den);
    return fminf(fmaxf(t, -1.0f), 1.0f);
}

__global__ __launch_bounds__(64, 1) void lstm_quad_pade_kernel(
    const float* __restrict__ x,
    const float* __restrict__ h0,
    const float* __restrict__ c0,
    const float* __restrict__ w_ih,
    const float* __restrict__ w_hh,
    const float* __restrict__ b_ih,
    const float* __restrict__ b_hh,
    float* __restrict__ out,
    int B, int T)
{
    const int tid = blockIdx.x * blockDim.x + threadIdx.x;
    const int e = tid >> 2;        // batch element
    const int q = tid & 3;         // lane within quad
    if (e >= B) return;

    // slotA rows: q0->i0(0) q1->i1(1) q2->g0(4) q3->g1(5); slotB = +2
    // (rows 0..7 of weights = i0,i1,f0,f1,g0,g1,o0,o1)
    const int rA = (q < 2) ? q : q + 2;
    const int rB = rA + 2;

    // slotA: sigmoid for q0/q1 (arg-scale 0.5, affine 0.5*t+0.5),
    //        tanh for q2/q3 (scale 1, affine t).
    const bool isTanh = (q >= 2);
    const float sA = isTanh ? 1.0f : 0.5f;
    const float mA = isTanh ? 1.0f : 0.5f;
    const float dA = isTanh ? 0.0f : 0.5f;

    const float wiA0 = w_ih[2 * rA] * sA, wiA1 = w_ih[2 * rA + 1] * sA;
    const float whA0 = w_hh[2 * rA] * sA, whA1 = w_hh[2 * rA + 1] * sA;
    const float biasA = (b_ih[rA] + b_hh[rA]) * sA;
    // slotB: always sigmoid (f for q0/q1, o for q2/q3) -> scale 0.5
    const float wiB0 = w_ih[2 * rB] * 0.5f, wiB1 = w_ih[2 * rB + 1] * 0.5f;
    const float whB0 = w_hh[2 * rB] * 0.5f, whB1 = w_hh[2 * rB + 1] * 0.5f;
    const float biasB = (b_ih[rB] + b_hh[rB]) * 0.5f;

    float h = h0[2 * e + (q & 1)];
    float c = c0[2 * e + (q & 1)];

    const int NI = T >> 1;  // float4s per element row (2 timesteps each)
    const float4* __restrict__ xp =
        reinterpret_cast<const float4*>(x) + (size_t)e * NI;

    auto step = [&](float x0, float x1) {
        float hh0 = qperm<QP_BCAST0>(h);
        float hh1 = qperm<QP_BCAST1>(h);
        // x-projection: off the h-dependency chain
        float axA = fmaf(wiA1, x1, fmaf(wiA0, x0, biasA));
        float axB = fmaf(wiB1, x1, fmaf(wiB0, x0, biasB));
        float gA = fmaf(whA1, hh1, fmaf(whA0, hh0, axA));
        float gB = fmaf(whB1, hh1, fmaf(whB0, hh0, axB));
        float nA = fmaf(mA, tanh_pade(gA), dA);       // sigma(i) | tanh(g)
        float nB = fmaf(0.5f, tanh_pade(gB), 0.5f);   // sigma(f) | sigma(o)
        float xA = qperm<QP_SWAP2>(nA);  // q0: tanh(g0), q1: tanh(g1)
        float xB = qperm<QP_SWAP2>(nB);  // q0: sigma(o0), q1: sigma(o1)
        c = fmaf(nB, c, nA * xA);
        float tc = tanh_pade(c);
        h = xB * tc;
    };

    constexpr int BV = 8;              // float4s per buffer = 16 timesteps
    float4 A[BV], Bb[BV];

    auto loadbuf = [&](float4* buf, int batch) {
#pragma unroll
        for (int j = 0; j < BV; ++j) buf[j] = xp[batch * BV + j];
    };
    auto consume = [&](const float4* buf) {
#pragma unroll
        for (int j = 0; j < BV; ++j) {
            step(buf[j].x, buf[j].y);
            step(buf[j].z, buf[j].w);
        }
    };

    const int nb = NI / BV;
    int bi = 0;
    if (nb >= 2) {
        loadbuf(A, 0);
        loadbuf(Bb, 1);
        for (bi = 0; bi + 1 < nb; bi += 2) {
            consume(A);
            if (bi + 2 < nb) loadbuf(A, bi + 2);
            consume(Bb);
            if (bi + 3 < nb) loadbuf(Bb, bi + 3);
        }
        if (bi < nb) { consume(A); ++bi; }
    }
    for (int i = bi * BV; i < NI; ++i) {   // tail (empty for T=2048)
        float4 v = xp[i];
        step(v.x, v.y);
        step(v.z, v.w);
    }

    if (q < 2) out[2 * e + q] = c;
}

extern "C" void kernel_launch(void* const* d_in, const int* in_sizes, int n_in,
                              void* d_out, int out_size, void* d_ws, size_t ws_size,
                              hipStream_t stream) {
    const float* x    = (const float*)d_in[0];
    const float* h0   = (const float*)d_in[1];
    const float* c0   = (const float*)d_in[2];
    const float* w_ih = (const float*)d_in[3];
    const float* w_hh = (const float*)d_in[4];
    const float* b_ih = (const float*)d_in[5];
    const float* b_hh = (const float*)d_in[6];
    float* out = (float*)d_out;

    const int B = in_sizes[1] / 2;           // h0 is (B, H=2)
    const int T = in_sizes[0] / (B * 2);     // x is (B, T, D=2)

    const int threads = B * 4;               // 4 lanes per element
    dim3 block(64);
    dim3 grid((threads + 63) / 64);
    hipLaunchKernelGGL(lstm_quad_pade_kernel, grid, block, 0, stream,
                       x, h0, c0, w_ih, w_hh, b_ih, b_hh, out, B, T);
}